// Round 5
// baseline (702.370 us; speedup 1.0000x reference)
//
#include <hip/hip_runtime.h>
#include <hip/hip_bf16.h>

#define EMBED 128
#define NRAD  16
#define OUTE  256

typedef __bf16 bf16x8 __attribute__((ext_vector_type(8)));
typedef float  f32x4  __attribute__((ext_vector_type(4)));

static __device__ __forceinline__ unsigned short f2bf(float x) {
    return __builtin_bit_cast(unsigned short, (__bf16)x);
}

// ---------------------------------------------------------------------------
// Phase 1a: histogram of receiving-atom indices.
// ---------------------------------------------------------------------------
__global__ __launch_bounds__(256) void hist_kernel(const int* __restrict__ idx_i,
                                                   int* __restrict__ counts, int n_edges)
{
    for (int e = blockIdx.x * blockDim.x + threadIdx.x; e < n_edges;
         e += gridDim.x * blockDim.x)
        atomicAdd(&counts[idx_i[e]], 1);
}

// ---------------------------------------------------------------------------
// Phase 1b: single-block exclusive scan. Writes immutable row_start[0..n]
// (gather reads start/end from here) and cursor[] (scatter mutates).
// ---------------------------------------------------------------------------
__global__ __launch_bounds__(1024) void scan_kernel(const int* __restrict__ counts,
                                                    int* __restrict__ row_start,
                                                    int* __restrict__ cursor, int n)
{
    __shared__ int partial[1024];
    const int tid = threadIdx.x;
    const int chunk = (n + 1023) / 1024;
    const int lo = min(tid * chunk, n), hi = min(lo + chunk, n);
    int s = 0;
    for (int i = lo; i < hi; ++i) s += counts[i];
    partial[tid] = s;
    __syncthreads();
    for (int off = 1; off < 1024; off <<= 1) {
        int v = (tid >= off) ? partial[tid - off] : 0;
        __syncthreads();
        partial[tid] += v;
        __syncthreads();
    }
    int run = (tid > 0) ? partial[tid - 1] : 0;
    for (int i = lo; i < hi; ++i) {
        row_start[i] = run;
        cursor[i] = run;
        run += counts[i];
    }
    if (tid == 1023) row_start[n] = run;   // run == total for the last thread
}

// ---------------------------------------------------------------------------
// Phase 1c: scatter edge ids into CSR order.
// ---------------------------------------------------------------------------
__global__ __launch_bounds__(256) void scatter_ids_kernel(const int* __restrict__ idx_i,
                                                          int* __restrict__ cursor,
                                                          int* __restrict__ edge_order,
                                                          int n_edges)
{
    for (int e = blockIdx.x * blockDim.x + threadIdx.x; e < n_edges;
         e += gridDim.x * blockDim.x) {
        const int pos = atomicAdd(&cursor[idx_i[e]], 1);
        edge_order[pos] = e;
    }
}

// ---------------------------------------------------------------------------
// Phase 1d: per-particle gather-reduce, 3-deep software pipeline.
// - wave loads the particle's edge-id window coalesced, broadcasts via shfl
// - rbf rows staged in wave-private LDS (consumed as wave-uniform broadcasts)
// - messages triple-buffered: group g+3 issued before group g computes
// - next particle's row_start bounds prefetched during current particle
// ---------------------------------------------------------------------------
__global__ __launch_bounds__(256, 4) void gather_reduce_kernel(
    const float* __restrict__ messages, const float* __restrict__ rbf,
    const int* __restrict__ edge_order, const int* __restrict__ row_start,
    const float* __restrict__ W_rbf,
    float* __restrict__ summed, int n_particles)
{
    __shared__ float rbf_s[4][64 * NRAD];   // 4 KB per wave, wave-private

    const int tid  = threadIdx.x;
    const int lane = tid & 63;
    const int wv   = tid >> 6;
    const int col  = lane * 2;
    float* lds = rbf_s[wv];

    float2 w[NRAD];
#pragma unroll
    for (int r = 0; r < NRAD; ++r)
        w[r] = *reinterpret_cast<const float2*>(&W_rbf[r * EMBED + col]);

    int p = blockIdx.x * 4 + wv;
    const int pstep = gridDim.x * 4;
    if (p >= n_particles) return;

    int start = row_start[p];
    int end   = row_start[p + 1];

    for (; p < n_particles; p += pstep) {
        // prefetch next particle's bounds (hides the metadata chain)
        const int pn = p + pstep;
        int startN = 0, endN = 0;
        if (pn < n_particles) {
            startN = row_start[pn];
            endN   = row_start[pn + 1];
        }

        float ax = 0.f, ay = 0.f;

        for (int w0 = start; w0 < end; w0 += 64) {
            const int n   = min(end - w0, 64);      // wave-uniform
            const int nm1 = n - 1;
            const int myid = edge_order[min(w0 + lane, end - 1)];

            // ---- stage rbf rows of this window into LDS ----
            const int subq = lane >> 4;
            const int rr   = lane & 15;
            const int ng   = (n + 3) >> 2;
            for (int g = 0; g < ng; ++g) {
                const int ei = g * 4 + subq;
                const int eq = __shfl(myid, min(ei, nm1), 64);
                lds[ei * NRAD + rr] = rbf[(long long)eq * NRAD + rr];
            }

            // ---- 3-deep message pipeline over 4-edge groups ----
            float2 m0[4], m1[4], m2[4];
            auto issue_grp = [&](float2* mb, int base) {
#pragma unroll
                for (int j = 0; j < 4; ++j) {
                    const int e = __shfl(myid, min(base + j, nm1), 64);
                    mb[j] = *reinterpret_cast<const float2*>(
                        messages + (long long)e * EMBED + col);
                }
            };
            issue_grp(m0, 0);
            issue_grp(m1, 4);
            issue_grp(m2, 8);

            for (int i = 0; i < n; i += 4) {
#pragma unroll
                for (int j = 0; j < 4; ++j) {
                    const float* lr = &lds[(i + j) * NRAD];
                    const float4 q0 = *reinterpret_cast<const float4*>(lr + 0);
                    const float4 q1 = *reinterpret_cast<const float4*>(lr + 4);
                    const float4 q2 = *reinterpret_cast<const float4*>(lr + 8);
                    const float4 q3 = *reinterpret_cast<const float4*>(lr + 12);
                    const float rv[NRAD] = {q0.x, q0.y, q0.z, q0.w,
                                            q1.x, q1.y, q1.z, q1.w,
                                            q2.x, q2.y, q2.z, q2.w,
                                            q3.x, q3.y, q3.z, q3.w};
                    float tx = 0.f, ty = 0.f;
#pragma unroll
                    for (int r = 0; r < NRAD; ++r) {
                        tx = fmaf(rv[r], w[r].x, tx);
                        ty = fmaf(rv[r], w[r].y, ty);
                    }
                    const float mk = (i + j < n) ? 1.f : 0.f;
                    ax = fmaf(m0[j].x * mk, tx, ax);
                    ay = fmaf(m0[j].y * mk, ty, ay);
                }
                // rotate buffers (static indices only) and refill the tail
#pragma unroll
                for (int j = 0; j < 4; ++j) { m0[j] = m1[j]; m1[j] = m2[j]; }
                if (i + 12 < n) issue_grp(m2, i + 12);
            }
        }

        *reinterpret_cast<float2*>(&summed[(long long)p * EMBED + col]) =
            make_float2(ax, ay);
        start = startN;
        end   = endN;
    }
}

// ---------------------------------------------------------------------------
// Weight prep: cast + transpose to bf16 W^T [N][K].
// ---------------------------------------------------------------------------
__global__ __launch_bounds__(256) void prep_weights_kernel(
    const float* __restrict__ Wup, const float* __restrict__ W1,
    const float* __restrict__ W2, const float* __restrict__ W3,
    __bf16* __restrict__ WupT, __bf16* __restrict__ W1T,
    __bf16* __restrict__ W2T, __bf16* __restrict__ W3T)
{
    const int total = OUTE * EMBED + 3 * OUTE * OUTE;
    for (int id = blockIdx.x * blockDim.x + threadIdx.x; id < total;
         id += gridDim.x * blockDim.x) {
        if (id < OUTE * EMBED) {
            const int n = id / EMBED, k = id % EMBED;
            WupT[id] = (__bf16)Wup[k * OUTE + n];
        } else {
            const int r = id - OUTE * EMBED;
            const int wsel = r / (OUTE * OUTE);
            const int rr = r % (OUTE * OUTE);
            const int n = rr / OUTE, k = rr % OUTE;
            const float* src = (wsel == 0) ? W1 : ((wsel == 1) ? W2 : W3);
            __bf16* dst = (wsel == 0) ? W1T : ((wsel == 1) ? W2T : W3T);
            dst[rr] = (__bf16)src[k * OUTE + n];
        }
    }
}

// ---------------------------------------------------------------------------
// Phase 2+3 fused: whole MLP for a 64-row tile, bf16 MFMA, h in LDS only.
// LDS: [64][256] bf16, byte ^= ((row&7)<<4) XOR swizzle (G4).
// ---------------------------------------------------------------------------
template <int K, bool ACT>
__device__ __forceinline__ void mlp_layer(const unsigned short* lin, unsigned short* lout,
                                          const __bf16* __restrict__ Wt,
                                          const float* __restrict__ bias, int l, int w)
{
    f32x4 acc[4][4];
#pragma unroll
    for (int i = 0; i < 4; ++i)
#pragma unroll
        for (int j = 0; j < 4; ++j)
            acc[i][j] = (f32x4){0.f, 0.f, 0.f, 0.f};

    const int lr = l & 15;
    const int hi = l >> 4;
    const int kg = hi * 8;

#pragma unroll
    for (int kk = 0; kk < K; kk += 32) {
        bf16x8 af[4], bf_[4];
#pragma unroll
        for (int i = 0; i < 4; ++i) {
            const int row = i * 16 + lr;
            const int byte = row * 512 + (((kk + kg) * 2) ^ ((row & 7) << 4));
            af[i] = *reinterpret_cast<const bf16x8*>(
                reinterpret_cast<const char*>(lin) + byte);
        }
#pragma unroll
        for (int j = 0; j < 4; ++j) {
            const int n = w * 64 + j * 16 + lr;
            bf_[j] = *reinterpret_cast<const bf16x8*>(Wt + (size_t)n * K + kk + kg);
        }
#pragma unroll
        for (int i = 0; i < 4; ++i)
#pragma unroll
            for (int j = 0; j < 4; ++j)
                acc[i][j] = __builtin_amdgcn_mfma_f32_16x16x32_bf16(af[i], bf_[j],
                                                                    acc[i][j], 0, 0, 0);
    }

    float bb[4];
#pragma unroll
    for (int j = 0; j < 4; ++j)
        bb[j] = ACT ? bias[w * 64 + j * 16 + lr] : 0.f;

#pragma unroll
    for (int j = 0; j < 4; ++j) {
        const int colb = (w * 64 + j * 16 + lr) * 2;
#pragma unroll
        for (int i = 0; i < 4; ++i) {
#pragma unroll
            for (int r = 0; r < 4; ++r) {
                const int row = i * 16 + hi * 4 + r;
                float v = acc[i][j][r];
                if (ACT) {
                    v += bb[j];
                    v = v / (1.f + __expf(-v));
                }
                const int byte = row * 512 + (colb ^ ((row & 7) << 4));
                *reinterpret_cast<unsigned short*>(
                    reinterpret_cast<char*>(lout) + byte) = f2bf(v);
            }
        }
    }
}

__global__ __launch_bounds__(256) void fused_mlp_kernel(
    const float* __restrict__ summed,
    const __bf16* __restrict__ WupT, const __bf16* __restrict__ W1T,
    const __bf16* __restrict__ W2T, const __bf16* __restrict__ W3T,
    const float* __restrict__ b1, const float* __restrict__ b2,
    const float* __restrict__ b3, const float* __restrict__ Wf,
    float* __restrict__ out, int M)
{
    __shared__ __align__(16) unsigned short buf0[64 * 256];
    __shared__ __align__(16) unsigned short buf1[64 * 256];

    const int tid = threadIdx.x;
    const int l = tid & 63, w = tid >> 6;
    const int row0 = blockIdx.x * 64;

#pragma unroll
    for (int i = 0; i < 8; ++i) {
        const int id = tid + i * 256;
        const int row = id >> 5;
        const int c = (id & 31) * 4;
        float4 v = make_float4(0.f, 0.f, 0.f, 0.f);
        const int gr = row0 + row;
        if (gr < M)
            v = *reinterpret_cast<const float4*>(summed + (long long)gr * EMBED + c);
        ushort4 u = make_ushort4(f2bf(v.x), f2bf(v.y), f2bf(v.z), f2bf(v.w));
        const int byte = row * 512 + ((c * 2) ^ ((row & 7) << 4));
        *reinterpret_cast<ushort4*>(reinterpret_cast<char*>(buf0) + byte) = u;
    }
    __syncthreads();

    mlp_layer<EMBED, false>(buf0, buf1, WupT, nullptr, l, w);
    __syncthreads();
    mlp_layer<OUTE, true>(buf1, buf0, W1T, b1, l, w);
    __syncthreads();
    mlp_layer<OUTE, true>(buf0, buf1, W2T, b2, l, w);
    __syncthreads();
    mlp_layer<OUTE, true>(buf1, buf0, W3T, b3, l, w);
    __syncthreads();

    const int row = tid >> 2, q = tid & 3;
    float s = 0.f;
#pragma unroll
    for (int c = 0; c < 8; ++c) {
        const int k = q * 64 + c * 8;
        const int byte = row * 512 + ((k * 2) ^ ((row & 7) << 4));
        const bf16x8 hv = *reinterpret_cast<const bf16x8*>(
            reinterpret_cast<const char*>(buf0) + byte);
        const float4 wa = *reinterpret_cast<const float4*>(Wf + k);
        const float4 wb = *reinterpret_cast<const float4*>(Wf + k + 4);
        s += (float)hv[0] * wa.x + (float)hv[1] * wa.y +
             (float)hv[2] * wa.z + (float)hv[3] * wa.w +
             (float)hv[4] * wb.x + (float)hv[5] * wb.y +
             (float)hv[6] * wb.z + (float)hv[7] * wb.w;
    }
    s += __shfl_xor(s, 1);
    s += __shfl_xor(s, 2);
    if (q == 0 && row0 + row < M) out[row0 + row] = s;
}

extern "C" void kernel_launch(void* const* d_in, const int* in_sizes, int n_in,
                              void* d_out, int out_size, void* d_ws, size_t ws_size,
                              hipStream_t stream)
{
    const float* messages = (const float*)d_in[0];
    const float* rbf      = (const float*)d_in[1];
    const int*   idx_i    = (const int*)d_in[2];
    // d_in[3] = idx_j (unused)
    const float* W_rbf    = (const float*)d_in[4];
    const float* W_up     = (const float*)d_in[5];
    const float* W1       = (const float*)d_in[6];
    const float* b1       = (const float*)d_in[7];
    const float* W2       = (const float*)d_in[8];
    const float* b2       = (const float*)d_in[9];
    const float* W3       = (const float*)d_in[10];
    const float* b3       = (const float*)d_in[11];
    const float* Wf       = (const float*)d_in[12];
    float* out = (float*)d_out;

    const int n_edges = in_sizes[2];
    const int M = out_size;

    char* ws = (char*)d_ws;
    size_t off = 0;
    float* summed = (float*)(ws + off); off += (size_t)M * EMBED * sizeof(float);
    int* counts     = (int*)(ws + off); off += (size_t)M * sizeof(int);
    int* row_start  = (int*)(ws + off); off += (size_t)(M + 1) * sizeof(int);
    int* cursor     = (int*)(ws + off); off += (size_t)M * sizeof(int);
    int* edge_order = (int*)(ws + off); off += (size_t)n_edges * sizeof(int);
    off = (off + 255) & ~(size_t)255;
    __bf16* WupT = (__bf16*)(ws + off); off += (size_t)OUTE * EMBED * 2;
    __bf16* W1T  = (__bf16*)(ws + off); off += (size_t)OUTE * OUTE * 2;
    __bf16* W2T  = (__bf16*)(ws + off); off += (size_t)OUTE * OUTE * 2;
    __bf16* W3T  = (__bf16*)(ws + off); off += (size_t)OUTE * OUTE * 2;

    hipMemsetAsync(counts, 0, (size_t)M * sizeof(int), stream);
    hist_kernel<<<4096, 256, 0, stream>>>(idx_i, counts, n_edges);
    scan_kernel<<<1, 1024, 0, stream>>>(counts, row_start, cursor, M);
    scatter_ids_kernel<<<4096, 256, 0, stream>>>(idx_i, cursor, edge_order, n_edges);
    prep_weights_kernel<<<896, 256, 0, stream>>>(W_up, W1, W2, W3, WupT, W1T, W2T, W3T);
    gather_reduce_kernel<<<2048, 256, 0, stream>>>(messages, rbf, edge_order, row_start,
                                                   W_rbf, summed, M);
    fused_mlp_kernel<<<(M + 63) / 64, 256, 0, stream>>>(summed, WupT, W1T, W2T, W3T,
                                                        b1, b2, b3, Wf, out, M);
}